// Round 4
// baseline (182.184 us; speedup 1.0000x reference)
//
#include <hip/hip_runtime.h>
#include <math.h>

// v4: LOOPED body (I-cache theory).
//
// Rounds 1-3: three different memory strategies, identical ~62us. Common
// factor: ~40KB fully-unrolled straight-line body -> instruction-fetch bound
// (I$ is 32KB-class; every wave streams the whole body from L2; occupancy
// can't hide front-end stalls -- round 2 had ~7 waves/SIMD and was equally
// slow). Fix: roll the pooled-row loop i=0..4 (unroll(disable)); row wrap
// via two selects; rows re-read from LDS each iter (dynamic LDS indexing is
// fine, ds_read_b64 8B-aligned, conflict-free). j stays unrolled so column
// wraps are compile-time. Body ~8KB -> I$-resident.

#define SREAD(x) __int_as_float(__builtin_amdgcn_readfirstlane(__float_as_int(x)))

__global__ __launch_bounds__(128) void CNN2D_37495064494620_kernel(
    const float* __restrict__ v,
    const float* __restrict__ cw,   // [4,1,3,3]
    const float* __restrict__ cb,   // [4]
    const float* __restrict__ dw,   // [4,1,2,2]
    const float* __restrict__ db,   // [1]
    float* __restrict__ out,        // [2*B]
    int B)
{
    const int tid = threadIdx.x;              // 128 threads = 2 waves
    const int b = blockIdx.x * 128 + tid;

    __shared__ __align__(16) float sm[128 * 100];   // 51.2 KB

    // Coalesced stage: 12800 floats; each instr: 128 lanes x 16B.
    // global_load_lds LDS dest = wave-uniform base + lane*16 -> per-wave base.
    const float* gbase = v + (size_t)blockIdx.x * 12800;
    const int widx = tid >> 6;
    #pragma unroll
    for (int k = 0; k < 25; ++k) {
        __builtin_amdgcn_global_load_lds(
            (const __attribute__((address_space(1))) void*)(gbase + k * 512 + tid * 4),
            (__attribute__((address_space(3))) void*)&sm[k * 512 + widx * 256],
            16, 0, 0);
    }

    // Wave-uniform weights -> SGPRs.
    float W[4][9];
    #pragma unroll
    for (int f = 0; f < 4; ++f)
        #pragma unroll
        for (int t = 0; t < 9; ++t)
            W[f][t] = SREAD(cw[f * 9 + t]);
    float Cb[4];
    #pragma unroll
    for (int f = 0; f < 4; ++f) Cb[f] = SREAD(cb[f]);
    float Dw[4][4];
    #pragma unroll
    for (int f = 0; f < 4; ++f)
        #pragma unroll
        for (int t = 0; t < 4; ++t)
            Dw[f][t] = SREAD(dw[f * 4 + t]);
    const float Db = SREAD(db[0]);

    __syncthreads();   // drains vmcnt of global_load_lds

    const int myoff = tid * 100;
    unsigned sbits = 0u;
    float l2 = 0.0f;

    #pragma clang loop unroll(disable)
    for (int i = 0; i < 5; ++i) {
        // Window rows 2i-1 .. 2i+2 (wrap) -- two selects, rest affine.
        const int rows[4] = { (i == 0) ? 9 : 2 * i - 1,
                              2 * i,
                              2 * i + 1,
                              (i == 4) ? 0 : 2 * i + 2 };
        float R[4][10];
        #pragma unroll
        for (int rr = 0; rr < 4; ++rr) {
            const int base = myoff + rows[rr] * 10;   // 8B-aligned (40B rows)
            #pragma unroll
            for (int t = 0; t < 5; ++t) {
                float2 q = *(const float2*)&sm[base + 2 * t];
                R[rr][2 * t]     = q.x;
                R[rr][2 * t + 1] = q.y;
            }
        }
        #pragma unroll
        for (int j = 0; j < 5; ++j) {
            float p0, p1, p2, p3;
            #pragma unroll
            for (int dr = 0; dr < 2; ++dr) {
                #pragma unroll
                for (int dc = 0; dc < 2; ++dc) {
                    float a0 = Cb[0], a1 = Cb[1], a2 = Cb[2], a3 = Cb[3];
                    #pragma unroll
                    for (int kr = 0; kr < 3; ++kr) {
                        #pragma unroll
                        for (int kc = 0; kc < 3; ++kc) {
                            const int cc = (2 * j + dc + kc + 9) % 10;  // compile-time
                            const float xv = R[dr + kr][cc];
                            const int t = kr * 3 + kc;
                            a0 = fmaf(xv, W[0][t], a0);
                            a1 = fmaf(xv, W[1][t], a1);
                            a2 = fmaf(xv, W[2][t], a2);
                            a3 = fmaf(xv, W[3][t], a3);
                        }
                    }
                    if (dr == 0 && dc == 0) {
                        p0 = a0; p1 = a1; p2 = a2; p3 = a3;
                    } else {
                        p0 = fmaxf(p0, a0); p1 = fmaxf(p1, a1);
                        p2 = fmaxf(p2, a2); p3 = fmaxf(p3, a3);
                    }
                }
            }
            float z[4];
            #pragma unroll
            for (int kl = 0; kl < 4; ++kl) {
                float zz = Db;
                zz = fmaf(p0, Dw[0][kl], zz);
                zz = fmaf(p1, Dw[1][kl], zz);
                zz = fmaf(p2, Dw[2][kl], zz);
                zz = fmaf(p3, Dw[3][kl], zz);
                z[kl] = zz;
                sbits ^= __float_as_uint(zz);
            }
            l2 += __log2f(fabsf(z[0] * z[1])) + __log2f(fabsf(z[2] * z[3]));
        }
    }

    out[b]     = (sbits & 0x80000000u) ? -1.0f : 1.0f;
    out[B + b] = l2 * 0.69314718055994531f;  // ln2 * sum(log2|z|)
}

extern "C" void kernel_launch(void* const* d_in, const int* in_sizes, int n_in,
                              void* d_out, int out_size, void* d_ws, size_t ws_size,
                              hipStream_t stream) {
    const float* v  = (const float*)d_in[0];
    const float* cw = (const float*)d_in[1];
    const float* cb = (const float*)d_in[2];
    const float* dw = (const float*)d_in[3];
    const float* db = (const float*)d_in[4];
    float* out = (float*)d_out;

    const int B = in_sizes[0] / 100;
    const int grid = (B + 127) / 128;
    CNN2D_37495064494620_kernel<<<grid, 128, 0, stream>>>(v, cw, cb, dw, db, out, B);
}

// Round 5
// 169.284 us; speedup vs baseline: 1.0762x; 1.0762x over previous
//
#include <hip/hip_runtime.h>
#include <math.h>

// v5: two lanes per sample -> halve LDS/wave, double occupancy.
//
// Round-4 evidence: OccupancyPercent 12% (~1 wave/SIMD), VALUBusy 41%.
// Whole-sample LDS staging (400B/sample, 64 samples/wave = 25.6KB) caps
// occupancy at ~6 waves/CU; a single wave can't hide its own latencies.
// Split each sample across a lane pair: parity q computes conv rows 2i+q
// (3 input rows each), pooling completed via __shfl_xor(1)+max; deconv/log
// redundant in both lanes (uniform, no divergence). 32 samples/wave =
// 12.8KB -> 12 waves/CU. Staging/SGPR-weights/sign-XOR/paired-logs kept.

#define SREAD(x) __int_as_float(__builtin_amdgcn_readfirstlane(__float_as_int(x)))

__device__ __forceinline__ void gload16(const float* g, float* l) {
    __builtin_amdgcn_global_load_lds(
        (const __attribute__((address_space(1))) void*)g,
        (__attribute__((address_space(3))) void*)l, 16, 0, 0);
}
__device__ __forceinline__ void gload4(const float* g, float* l) {
    __builtin_amdgcn_global_load_lds(
        (const __attribute__((address_space(1))) void*)g,
        (__attribute__((address_space(3))) void*)l, 4, 0, 0);
}

__global__ __launch_bounds__(64) void CNN2D_37495064494620_kernel(
    const float* __restrict__ v,
    const float* __restrict__ cw,   // [4,1,3,3]
    const float* __restrict__ cb,   // [4]
    const float* __restrict__ dw,   // [4,1,2,2]
    const float* __restrict__ db,   // [1]
    float* __restrict__ out,        // [2*B]
    int B)
{
    const int l  = threadIdx.x;     // block = 1 wave
    const int q  = l & 1;           // conv-row parity this lane handles
    const int sl = l >> 1;          // local sample 0..31

    __shared__ __align__(16) float sm[3200];   // 32 samples x 100 = 12.8 KB

    // Coalesced stage of 12800 B: 12 x (64 lanes x 16B) + 2 x (64 lanes x 4B).
    const float* gbase = v + (size_t)blockIdx.x * 3200;
    #pragma unroll
    for (int k = 0; k < 12; ++k)
        gload16(gbase + k * 256 + l * 4, &sm[k * 256]);
    #pragma unroll
    for (int k = 0; k < 2; ++k)
        gload4(gbase + 3072 + k * 64 + l, &sm[3072 + k * 64]);

    // Wave-uniform weights -> SGPRs.
    float W[4][9];
    #pragma unroll
    for (int f = 0; f < 4; ++f)
        #pragma unroll
        for (int t = 0; t < 9; ++t)
            W[f][t] = SREAD(cw[f * 9 + t]);
    float Cb[4];
    #pragma unroll
    for (int f = 0; f < 4; ++f) Cb[f] = SREAD(cb[f]);
    float Dw[4][4];
    #pragma unroll
    for (int f = 0; f < 4; ++f)
        #pragma unroll
        for (int t = 0; t < 4; ++t)
            Dw[f][t] = SREAD(dw[f * 4 + t]);
    const float Db = SREAD(db[0]);

    __syncthreads();   // drain staging

    const float* my = sm + sl * 100;

    unsigned sbits = 0u;
    float l2 = 0.0f;

    #pragma unroll
    for (int i = 0; i < 5; ++i) {
        // This lane's conv row r1 = 2i+q; window = input rows r1-1, r1, r1+1 (wrap).
        const int r1 = 2 * i + q;
        const int r0 = (i == 0) ? (q ? 0 : 9) : (2 * i - 1 + q);  // wrap at i=0,q=0
        const int r2 = (i == 4) ? (q ? 0 : 9) : (2 * i + 1 + q);  // wrap at i=4,q=1

        float R[3][10];
        #pragma unroll
        for (int t = 0; t < 5; ++t) {
            float2 x0 = *(const float2*)(my + r0 * 10 + 2 * t);
            float2 x1 = *(const float2*)(my + r1 * 10 + 2 * t);
            float2 x2 = *(const float2*)(my + r2 * 10 + 2 * t);
            R[0][2 * t] = x0.x; R[0][2 * t + 1] = x0.y;
            R[1][2 * t] = x1.x; R[1][2 * t + 1] = x1.y;
            R[2][2 * t] = x2.x; R[2][2 * t + 1] = x2.y;
        }

        // Conv row 2i+q at columns 2j (dc=0) and 2j+1 (dc=1), maxed over dc.
        float M[5][4];
        #pragma unroll
        for (int j = 0; j < 5; ++j) {
            float a0[4], a1[4];
            #pragma unroll
            for (int f = 0; f < 4; ++f) { a0[f] = Cb[f]; a1[f] = Cb[f]; }
            #pragma unroll
            for (int kr = 0; kr < 3; ++kr) {
                #pragma unroll
                for (int kc = 0; kc < 3; ++kc) {
                    const int cc0 = (2 * j + kc + 9) % 10;       // dc=0, compile-time
                    const int cc1 = (2 * j + 1 + kc + 9) % 10;   // dc=1
                    const float x0 = R[kr][cc0];
                    const float x1 = R[kr][cc1];
                    const int t = kr * 3 + kc;
                    #pragma unroll
                    for (int f = 0; f < 4; ++f) {
                        a0[f] = fmaf(x0, W[f][t], a0[f]);
                        a1[f] = fmaf(x1, W[f][t], a1[f]);
                    }
                }
            }
            #pragma unroll
            for (int f = 0; f < 4; ++f)
                M[j][f] = fmaxf(a0[f], a1[f]);
        }

        // Complete the 2x2 pool across the lane pair (partner has row 2i+(1-q)).
        float P[5][4];
        #pragma unroll
        for (int j = 0; j < 5; ++j)
            #pragma unroll
            for (int f = 0; f < 4; ++f)
                P[j][f] = fmaxf(M[j][f], __shfl_xor(M[j][f], 1));

        // Deconv + sign + log: identical in both lanes of the pair (uniform).
        #pragma unroll
        for (int j = 0; j < 5; ++j) {
            float z[4];
            #pragma unroll
            for (int kl = 0; kl < 4; ++kl) {
                float zz = Db;
                #pragma unroll
                for (int f = 0; f < 4; ++f)
                    zz = fmaf(P[j][f], Dw[f][kl], zz);
                z[kl] = zz;
                sbits ^= __float_as_uint(zz);
            }
            l2 += __log2f(fabsf(z[0] * z[1])) + __log2f(fabsf(z[2] * z[3]));
        }
    }

    // q=0 lane writes sign product, q=1 lane writes log-sum (values identical
    // in both lanes; single uniform store, no divergence).
    const int s = blockIdx.x * 32 + sl;
    const float val = q ? (l2 * 0.69314718055994531f)
                        : ((sbits & 0x80000000u) ? -1.0f : 1.0f);
    out[q * B + s] = val;
}

extern "C" void kernel_launch(void* const* d_in, const int* in_sizes, int n_in,
                              void* d_out, int out_size, void* d_ws, size_t ws_size,
                              hipStream_t stream) {
    const float* v  = (const float*)d_in[0];
    const float* cw = (const float*)d_in[1];
    const float* cb = (const float*)d_in[2];
    const float* dw = (const float*)d_in[3];
    const float* db = (const float*)d_in[4];
    float* out = (float*)d_out;

    const int B = in_sizes[0] / 100;       // 262144
    const int grid = B / 32;               // 32 samples per 64-lane block
    CNN2D_37495064494620_kernel<<<grid, 64, 0, stream>>>(v, cw, cb, dw, db, out, B);
}

// Round 6
// 168.740 us; speedup vs baseline: 1.0797x; 1.0032x over previous
//
#include <hip/hip_runtime.h>
#include <math.h>

// v6: packed-fp32 math + DPP pooling + de-duplicated tail.
//
// Evidence: r4 VALU-issue ~27us (66us x 41%); r5 (2-lane split, 12.8KB/wave)
// ~57us -- both VALU and LDS pipes loaded ~20us each with lgkmcnt stalls.
// Changes: (1) conv packed over the FILTER dim -> v_pk_fma_f32 (halves VALU
// instrs, no repack movs: weights pair in SGPRs, activation broadcast);
// (2) pool partner-max via DPP quad_perm(1,0,3,2) -- VALU, not ds_bpermute;
// (3) lane q computes only z[2q],z[2q+1] + its logs; pair-combine via DPP;
// (4) 256-thread blocks (128 samples, 51.2KB LDS, 3 blocks/CU = 12 waves).

typedef float v2f __attribute__((ext_vector_type(2)));

#define SREAD(x) __int_as_float(__builtin_amdgcn_readfirstlane(__float_as_int(x)))

__device__ __forceinline__ float dpp_swap1_f(float x) {
    return __int_as_float(__builtin_amdgcn_mov_dpp(__float_as_int(x), 0xB1, 0xF, 0xF, true));
}
__device__ __forceinline__ unsigned dpp_swap1_u(unsigned x) {
    return (unsigned)__builtin_amdgcn_mov_dpp((int)x, 0xB1, 0xF, 0xF, true);
}

__device__ __forceinline__ void gload16(const float* g, float* l) {
    __builtin_amdgcn_global_load_lds(
        (const __attribute__((address_space(1))) void*)g,
        (__attribute__((address_space(3))) void*)l, 16, 0, 0);
}
__device__ __forceinline__ void gload4(const float* g, float* l) {
    __builtin_amdgcn_global_load_lds(
        (const __attribute__((address_space(1))) void*)g,
        (__attribute__((address_space(3))) void*)l, 4, 0, 0);
}

__global__ __launch_bounds__(256) void CNN2D_37495064494620_kernel(
    const float* __restrict__ v,
    const float* __restrict__ cw,   // [4,1,3,3]
    const float* __restrict__ cb,   // [4]
    const float* __restrict__ dw,   // [4,1,2,2]
    const float* __restrict__ db,   // [1]
    float* __restrict__ out,        // [2*B]
    int B)
{
    const int tid = threadIdx.x;          // 256 threads = 4 waves
    const int q   = tid & 1;              // conv-row parity / kl-pair owner
    const int sl  = tid >> 1;             // local sample 0..127

    __shared__ __align__(16) float sm[12800];   // 128 samples x 100 = 51.2 KB

    // Coalesced stage: 12 x (256 lanes x 16B) + 2 x (256 lanes x 4B).
    const float* gbase = v + (size_t)blockIdx.x * 12800;
    const int widx = tid >> 6;
    #pragma unroll
    for (int k = 0; k < 12; ++k)
        gload16(gbase + k * 1024 + tid * 4, &sm[k * 1024 + widx * 256]);
    #pragma unroll
    for (int k = 0; k < 2; ++k)
        gload4(gbase + 12288 + k * 256 + tid, &sm[12288 + k * 256 + widx * 64]);

    // Wave-uniform weights -> SGPRs; conv weights packed over filter pairs.
    float Wf[4][9];
    #pragma unroll
    for (int f = 0; f < 4; ++f)
        #pragma unroll
        for (int t = 0; t < 9; ++t)
            Wf[f][t] = SREAD(cw[f * 9 + t]);
    v2f W2[9][2];
    #pragma unroll
    for (int t = 0; t < 9; ++t) {
        W2[t][0] = (v2f){Wf[0][t], Wf[1][t]};
        W2[t][1] = (v2f){Wf[2][t], Wf[3][t]};
    }
    const v2f Cb2[2] = { (v2f){SREAD(cb[0]), SREAD(cb[1])},
                         (v2f){SREAD(cb[2]), SREAD(cb[3])} };
    float Dw[4][4];
    #pragma unroll
    for (int f = 0; f < 4; ++f)
        #pragma unroll
        for (int t = 0; t < 4; ++t)
            Dw[f][t] = SREAD(dw[f * 4 + t]);
    const float Db = SREAD(db[0]);

    // This lane's deconv kl-pair weights: kl = 2q, 2q+1 (lane-dependent select).
    v2f Dq[4];
    #pragma unroll
    for (int f = 0; f < 4; ++f)
        Dq[f] = (v2f){ q ? Dw[f][2] : Dw[f][0], q ? Dw[f][3] : Dw[f][1] };

    __syncthreads();   // drain staging

    const float* my = sm + sl * 100;

    unsigned sbits = 0u;   // XOR of this lane's z sign bits (partial)
    float l2 = 0.0f;       // this lane's partial sum of log2|z|

    #pragma unroll
    for (int i = 0; i < 5; ++i) {
        // This lane's conv row r1 = 2i+q; window rows r1-1, r1, r1+1 (wrap).
        const int r1 = 2 * i + q;
        const int r0 = (i == 0) ? (q ? 0 : 9) : (2 * i - 1 + q);
        const int r2 = (i == 4) ? (q ? 0 : 9) : (2 * i + 1 + q);

        float R[3][10];
        #pragma unroll
        for (int t = 0; t < 5; ++t) {
            float2 x0 = *(const float2*)(my + r0 * 10 + 2 * t);
            float2 x1 = *(const float2*)(my + r1 * 10 + 2 * t);
            float2 x2 = *(const float2*)(my + r2 * 10 + 2 * t);
            R[0][2 * t] = x0.x; R[0][2 * t + 1] = x0.y;
            R[1][2 * t] = x1.x; R[1][2 * t + 1] = x1.y;
            R[2][2 * t] = x2.x; R[2][2 * t + 1] = x2.y;
        }

        #pragma unroll
        for (int j = 0; j < 5; ++j) {
            // Conv at columns 2j (dc=0) and 2j+1 (dc=1); filters packed in pairs.
            v2f a0[2] = {Cb2[0], Cb2[1]};   // dc=0: (f0,f1),(f2,f3)
            v2f a1[2] = {Cb2[0], Cb2[1]};   // dc=1
            #pragma unroll
            for (int kr = 0; kr < 3; ++kr) {
                #pragma unroll
                for (int kc = 0; kc < 3; ++kc) {
                    const int cc0 = (2 * j + kc + 9) % 10;       // compile-time
                    const int cc1 = (2 * j + 1 + kc + 9) % 10;
                    const int t = kr * 3 + kc;
                    const v2f x0 = (v2f){R[kr][cc0], R[kr][cc0]};
                    const v2f x1 = (v2f){R[kr][cc1], R[kr][cc1]};
                    a0[0] = __builtin_elementwise_fma(x0, W2[t][0], a0[0]);
                    a0[1] = __builtin_elementwise_fma(x0, W2[t][1], a0[1]);
                    a1[0] = __builtin_elementwise_fma(x1, W2[t][0], a1[0]);
                    a1[1] = __builtin_elementwise_fma(x1, W2[t][1], a1[1]);
                }
            }
            // dc-merge (packed max), then pool across the lane pair via DPP.
            const v2f m0 = __builtin_elementwise_max(a0[0], a1[0]);
            const v2f m1 = __builtin_elementwise_max(a0[1], a1[1]);
            float P[4];
            P[0] = fmaxf(m0.x, dpp_swap1_f(m0.x));
            P[1] = fmaxf(m0.y, dpp_swap1_f(m0.y));
            P[2] = fmaxf(m1.x, dpp_swap1_f(m1.x));
            P[3] = fmaxf(m1.y, dpp_swap1_f(m1.y));

            // Deconv: this lane owns kl = 2q, 2q+1 only.
            v2f z2 = (v2f){Db, Db};
            #pragma unroll
            for (int f = 0; f < 4; ++f) {
                const v2f pf = (v2f){P[f], P[f]};
                z2 = __builtin_elementwise_fma(pf, Dq[f], z2);
            }
            sbits ^= __float_as_uint(z2.x) ^ __float_as_uint(z2.y);
            l2 += __log2f(fabsf(z2.x * z2.y));
        }
    }

    // Combine partials across the lane pair (both lanes end with totals).
    l2 = l2 + dpp_swap1_f(l2);
    sbits = sbits ^ dpp_swap1_u(sbits);

    // q=0 lane writes sign product, q=1 lane writes log-sum.
    const int s = blockIdx.x * 128 + sl;
    const float val = q ? (l2 * 0.69314718055994531f)
                        : ((sbits & 0x80000000u) ? -1.0f : 1.0f);
    out[q * B + s] = val;
}

extern "C" void kernel_launch(void* const* d_in, const int* in_sizes, int n_in,
                              void* d_out, int out_size, void* d_ws, size_t ws_size,
                              hipStream_t stream) {
    const float* v  = (const float*)d_in[0];
    const float* cw = (const float*)d_in[1];
    const float* cb = (const float*)d_in[2];
    const float* dw = (const float*)d_in[3];
    const float* db = (const float*)d_in[4];
    float* out = (float*)d_out;

    const int B = in_sizes[0] / 100;       // 262144
    const int grid = B / 128;              // 128 samples per 256-thread block
    CNN2D_37495064494620_kernel<<<grid, 256, 0, stream>>>(v, cw, cb, dw, db, out, B);
}